// Round 6
// baseline (161.122 us; speedup 1.0000x reference)
//
#include <hip/hip_runtime.h>

#define NQ 50000
#define NS 50000
#define MNB 32
#define KP 15
#define DF 64
#define WTS 968             // wt LDS row stride in ushorts (960 + 8 pad)

typedef __bf16 bf16x8 __attribute__((ext_vector_type(8)));
typedef float  f32x4  __attribute__((ext_vector_type(4)));
typedef float  f32x2  __attribute__((ext_vector_type(2)));

__device__ __forceinline__ unsigned short f2bf(float f) {
    union { float f; unsigned int u; } v; v.f = f;
    unsigned int u = v.u;
    return (unsigned short)((u + 0x7FFFu + ((u >> 16) & 1u)) >> 16);  // RNE
}

// ---------------------------------------------------------------------------
// Preconvert weight [960][64] f32 -> bf16, B-fragment-swizzled:
// uint4 chunk t*64+c (t=0..119, c=0..63) holds W[t*8+j][c], j=0..7.
// MFMA step ks, quad q: B-fragment = chunk (4ks+q)*64 + col.
// ---------------------------------------------------------------------------
__global__ __launch_bounds__(256) void conv_w(const float* __restrict__ W,
                                              uint4* __restrict__ wBf) {
    const int chunk = blockIdx.x * 256 + threadIdx.x;
    if (chunk >= 7680) return;
    const int t = chunk >> 6, c = chunk & 63;
    union { unsigned short s[8]; uint4 u; } pk;
    #pragma unroll
    for (int j = 0; j < 8; ++j)
        pk.s[j] = f2bf(W[(size_t)(t * 8 + j) * 64 + c]);
    wBf[chunk] = pk.u;
}

// ---------------------------------------------------------------------------
// Fused KPConv, 8 queries per 256-thread block (grid = 6250, exact).
// No barrier between phases A and B: each half-wave only touches its own
// slot's LDS rows (same-wave LDS ordering). Active list padded to a multiple
// of 8 with sentinel entries (zero-weight row 32) -> uniform 8-wide batches,
// 8 gathers in flight, 2 ds_read_b128 per batch for the entry list.
// Single __syncthreads before the MFMA phase.
// ---------------------------------------------------------------------------
__global__ __launch_bounds__(256, 4) void kpconv_fused(
    const float* __restrict__ qp, const float* __restrict__ sp,
    const int* __restrict__ nb, const float* __restrict__ x,
    const float* __restrict__ kpts, const uint4* __restrict__ wBf,
    float* __restrict__ out)
{
    __shared__ struct {
        __align__(16) unsigned short wt[8 * WTS];   // MUST be first: phase-2
        __align__(16) float w[8][33][16];           //  A-rows 8..15 read this
        __align__(16) unsigned int am[8][MNB];      //  region (garbage OK)
    } sm;

    const int tid = threadIdx.x;
    const int lane = tid & 63, wv = tid >> 6;
    const int h = lane >> 5, m = lane & 31;
    const int slot = wv * 2 + h;                 // query slot 0..7
    const int n0 = blockIdx.x * 8;
    const int n = n0 + slot;                     // grid exact: n < NQ always

    // zero the sentinel weight row (row 32) for this slot
    if (m < 16) sm.w[slot][32][m] = 0.0f;

    // ---- phase A: lane m -> 15 influence weights for neighbor m
    const int id = nb[n * MNB + m];
    const float qx = qp[n * 3 + 0], qy = qp[n * 3 + 1], qz = qp[n * 3 + 2];
    float sx = 1e6f, sy = 1e6f, sz = 1e6f;
    if (id < NS) { sx = sp[id * 3 + 0]; sy = sp[id * 3 + 1]; sz = sp[id * 3 + 2]; }
    const float rx = sx - qx, ry = sy - qy, rz = sz - qz;
    float wk[KP], wmax = 0.0f;
    #pragma unroll
    for (int k = 0; k < KP; ++k) {               // kpts: uniform -> s_load
        const float dx = rx - kpts[k * 3 + 0];
        const float dy = ry - kpts[k * 3 + 1];
        const float dz = rz - kpts[k * 3 + 2];
        const float d2 = dx * dx + dy * dy + dz * dz;
        wk[k] = fmaxf(1.0f - sqrtf(d2), 0.0f);
        wmax = fmaxf(wmax, wk[k]);
    }
    const bool any = (wmax > 0.0f);
    if (any) {
        float4* wr = (float4*)&sm.w[slot][m][0];
        wr[0] = make_float4(wk[0], wk[1], wk[2], wk[3]);
        wr[1] = make_float4(wk[4], wk[5], wk[6], wk[7]);
        wr[2] = make_float4(wk[8], wk[9], wk[10], wk[11]);
        wr[3] = make_float4(wk[12], wk[13], wk[14], 0.0f);
    }
    const unsigned long long bal = __ballot(any);
    const unsigned int hm = (unsigned int)(bal >> (h * 32));
    if (any) {
        const int pos = __popc(hm & ((1u << m) - 1u));
        sm.am[slot][pos] = ((unsigned)id << 6) | (unsigned)m;   // row = e & 63
    }
    const int A = __popc(hm);
    const int Apad = (A + 7) & ~7;
    if (m < Apad - A) sm.am[slot][A + m] = 32u;  // sentinel: id 0, zero row 32

    // ---- phase B: lane = channel pair c; 8-wide batches, no barrier needed
    const int c = m;
    const float2* __restrict__ x2 = (const float2*)x;
    f32x2 acc[KP];
    #pragma unroll
    for (int k = 0; k < KP; ++k) acc[k] = (f32x2){0.f, 0.f};

#define ACCUM(E, F)                                                         \
    {                                                                       \
        const float4* wr = (const float4*)&sm.w[slot][(E) & 63u][0];        \
        const float4 w0 = wr[0], w1 = wr[1], w2 = wr[2], w3 = wr[3];        \
        acc[0]  += (F) * w0.x;  acc[1]  += (F) * w0.y;                      \
        acc[2]  += (F) * w0.z;  acc[3]  += (F) * w0.w;                      \
        acc[4]  += (F) * w1.x;  acc[5]  += (F) * w1.y;                      \
        acc[6]  += (F) * w1.z;  acc[7]  += (F) * w1.w;                      \
        acc[8]  += (F) * w2.x;  acc[9]  += (F) * w2.y;                      \
        acc[10] += (F) * w2.z;  acc[11] += (F) * w2.w;                      \
        acc[12] += (F) * w3.x;  acc[13] += (F) * w3.y;  acc[14] += (F) * w3.z; \
    }

    for (int j0 = 0; j0 < Apad; j0 += 8) {
        const uint4 ea = *(const uint4*)&sm.am[slot][j0];       // 8 entries via
        const uint4 eb = *(const uint4*)&sm.am[slot][j0 + 4];   // 2 ds_read_b128
        const float2 t0 = x2[(size_t)(ea.x >> 6) * 32 + c];     // 8 gathers
        const float2 t1 = x2[(size_t)(ea.y >> 6) * 32 + c];     //  in flight
        const float2 t2 = x2[(size_t)(ea.z >> 6) * 32 + c];
        const float2 t3 = x2[(size_t)(ea.w >> 6) * 32 + c];
        const float2 t4 = x2[(size_t)(eb.x >> 6) * 32 + c];
        const float2 t5 = x2[(size_t)(eb.y >> 6) * 32 + c];
        const float2 t6 = x2[(size_t)(eb.z >> 6) * 32 + c];
        const float2 t7 = x2[(size_t)(eb.w >> 6) * 32 + c];
        const f32x2 f0 = (f32x2){t0.x, t0.y}, f1 = (f32x2){t1.x, t1.y};
        const f32x2 f2 = (f32x2){t2.x, t2.y}, f3 = (f32x2){t3.x, t3.y};
        const f32x2 f4 = (f32x2){t4.x, t4.y}, f5 = (f32x2){t5.x, t5.y};
        const f32x2 f6 = (f32x2){t6.x, t6.y}, f7 = (f32x2){t7.x, t7.y};
        ACCUM(ea.x, f0) ACCUM(ea.y, f1) ACCUM(ea.z, f2) ACCUM(ea.w, f3)
        ACCUM(eb.x, f4) ACCUM(eb.y, f5) ACCUM(eb.z, f6) ACCUM(eb.w, f7)
    }
#undef ACCUM

    // bf16 row into wt tile
    unsigned int* wrow = (unsigned int*)sm.wt + slot * (WTS / 2);
    #pragma unroll
    for (int k = 0; k < KP; ++k)
        wrow[k * 32 + c] = (unsigned)f2bf(acc[k].x) | ((unsigned)f2bf(acc[k].y) << 16);
    __syncthreads();                             // the ONLY block barrier

    // ---- phase 2: MFMA. wave wv -> out cols [wv*16, wv*16+16)
    const int cl = lane & 15, q = lane >> 4;
    f32x4 dacc = (f32x4){0.f, 0.f, 0.f, 0.f};
    #pragma unroll 6
    for (int ks = 0; ks < 30; ++ks) {
        // A: lane holds wt[r=cl][32ks + 8q + j], j=0..7 (rows >=8: garbage)
        const bf16x8 a = *(const bf16x8*)&sm.wt[cl * WTS + ks * 32 + q * 8];
        // B: pre-swizzled chunk (4ks+q)*64 + (wv*16+cl), 256B coalesced
        union { uint4 u; bf16x8 v; } bu;
        bu.u = wBf[(4 * ks + q) * 64 + wv * 16 + cl];
        dacc = __builtin_amdgcn_mfma_f32_16x16x32_bf16(a, bu.v, dacc, 0, 0, 0);
    }
    // D: row = q*4+i; only rows 0..7 are real queries
    if (q < 2) {
        #pragma unroll
        for (int i = 0; i < 4; ++i)
            out[(size_t)(n0 + q * 4 + i) * 64 + wv * 16 + cl] = dacc[i];
    }
}

// ---------------------------------------------------------------------------
extern "C" void kernel_launch(void* const* d_in, const int* in_sizes, int n_in,
                              void* d_out, int out_size, void* d_ws, size_t ws_size,
                              hipStream_t stream) {
    const float* qp   = (const float*)d_in[0];
    const float* sp   = (const float*)d_in[1];
    const int*   nb   = (const int*)d_in[2];
    const float* x    = (const float*)d_in[3];
    const float* kpts = (const float*)d_in[4];
    const float* W    = (const float*)d_in[5];
    float* out = (float*)d_out;

    uint4* wBf = (uint4*)d_ws;   // 122880 B pre-swizzled bf16 weight

    hipLaunchKernelGGL(conv_w, dim3(30), dim3(256), 0, stream, W, wBf);
    hipLaunchKernelGGL(kpconv_fused, dim3(NQ / 8), dim3(256), 0, stream,
                       qp, sp, nb, x, kpts, wBf, out);
}

// Round 7
// 140.559 us; speedup vs baseline: 1.1463x; 1.1463x over previous
//
#include <hip/hip_runtime.h>

#define NQ 50000
#define NS 50000
#define MNB 32
#define KP 15
#define DF 64
#define WTS 968             // wt LDS row stride in ushorts (960 + 8 pad: 2-way banks)

typedef __bf16 bf16x8 __attribute__((ext_vector_type(8)));
typedef float  f32x4  __attribute__((ext_vector_type(4)));

__device__ __forceinline__ unsigned short f2bf(float f) {
    union { float f; unsigned int u; } v; v.f = f;
    unsigned int u = v.u;
    return (unsigned short)((u + 0x7FFFu + ((u >> 16) & 1u)) >> 16);  // RNE
}

// ---------------------------------------------------------------------------
// Preconvert weight [960][64] f32 -> bf16, B-fragment-swizzled:
// uint4 chunk t*64+c (t=0..119, c=0..63) holds W[t*8+j][c], j=0..7.
// MFMA step ks, quad q: B-fragment = chunk (4ks+q)*64 + col.
// ---------------------------------------------------------------------------
__global__ __launch_bounds__(256) void conv_w(const float* __restrict__ W,
                                              uint4* __restrict__ wBf) {
    const int chunk = blockIdx.x * 256 + threadIdx.x;
    if (chunk >= 7680) return;
    const int t = chunk >> 6, c = chunk & 63;
    union { unsigned short s[8]; uint4 u; } pk;
    #pragma unroll
    for (int j = 0; j < 8; ++j)
        pk.s[j] = f2bf(W[(size_t)(t * 8 + j) * 64 + c]);
    wBf[chunk] = pk.u;
}

// ---------------------------------------------------------------------------
// Fused KPConv: 16 queries per 1024-thread block (16 waves; grid 3125 exact).
// One query per wave: phase A splits the 15 kernel points across the two
// 32-lane halves (lane = neighbor m); phase B is scalar-channel (lane = d),
// looping over the compacted active-neighbor list in 4-wide batches
// (sentinel entries -> zero weight row 32). No intra-wave barriers; one
// __syncthreads before phase 2, where waves 0-3 do a full 16-row MFMA chain.
// ---------------------------------------------------------------------------
__global__ __launch_bounds__(1024, 8) void kpconv_fused(
    const float* __restrict__ qp, const float* __restrict__ sp,
    const int* __restrict__ nb, const float* __restrict__ x,
    const float* __restrict__ kpts, const uint4* __restrict__ wBf,
    float* __restrict__ out)
{
    __shared__ struct {
        __align__(16) unsigned short wt[16 * WTS];  // 30976 B: MFMA A-tile
        __align__(16) float w[16][33][20];          // 42240 B: stride 20 = conflict-free (r3)
        __align__(16) unsigned int am[16][MNB];     //  2048 B: compacted (id<<6)|m
    } sm;                                           // 75264 B -> 2 blocks/CU

    const int tid  = threadIdx.x;
    const int lane = tid & 63, wv = tid >> 6;       // wv = query slot 0..15
    const int kh = lane >> 5, m = lane & 31;
    const int n0 = blockIdx.x * 16;
    const int n  = n0 + wv;                          // exact grid: n < NQ

    // zero the sentinel weight row (row 32) for this slot (same-wave ordering)
    if (lane < 20) sm.w[wv][32][lane] = 0.0f;

    // ---- phase A: lane (m, kh) -> 8 influence weights for neighbor m
    const int id = nb[n * MNB + m];
    const float qx = qp[n * 3 + 0], qy = qp[n * 3 + 1], qz = qp[n * 3 + 2];
    float sx = 1e6f, sy = 1e6f, sz = 1e6f;
    if (id < NS) { sx = sp[id * 3 + 0]; sy = sp[id * 3 + 1]; sz = sp[id * 3 + 2]; }
    const float rx = sx - qx, ry = sy - qy, rz = sz - qz;
    float wk[8], wmax = 0.0f;
    const int kbase = kh * 8;
    #pragma unroll
    for (int j = 0; j < 8; ++j) {
        const int k = kbase + j;
        const int kc = (k < KP) ? k : 0;            // avoid OOB for k=15
        const float dx = rx - kpts[kc * 3 + 0];
        const float dy = ry - kpts[kc * 3 + 1];
        const float dz = rz - kpts[kc * 3 + 2];
        float wkj = fmaxf(1.0f - sqrtf(dx * dx + dy * dy + dz * dz), 0.0f);
        if (k >= KP) wkj = 0.0f;
        wk[j] = wkj;
        wmax = fmaxf(wmax, wkj);
    }
    const unsigned long long bal = __ballot(wmax > 0.0f);
    const unsigned int comb = (unsigned int)(bal & 0xFFFFFFFFull) |
                              (unsigned int)(bal >> 32);
    const int A = __popc(comb);
    const int Apad = (A + 3) & ~3;
    const bool act = (comb >> m) & 1u;
    if (act) {                                       // write this half's 8 weights
        float4* wr = (float4*)&sm.w[wv][m][0];
        wr[kh * 2 + 0] = make_float4(wk[0], wk[1], wk[2], wk[3]);
        wr[kh * 2 + 1] = make_float4(wk[4], wk[5], wk[6], wk[7]);
    }
    if (kh == 0) {
        if (act) {
            const int pos = __popc(comb & ((1u << m) - 1u));
            sm.am[wv][pos] = ((unsigned)id << 6) | (unsigned)m;   // row = e & 63
        }
        if (m < Apad - A) sm.am[wv][A + m] = 32u;   // sentinel: id 0, zero row 32
    }
    // no barrier: this wave reads only its own slot's LDS rows below

    // ---- phase B: lane = channel d; 4-wide batches over active list
    const int d = lane;
    float acc[KP];
    #pragma unroll
    for (int k = 0; k < KP; ++k) acc[k] = 0.0f;

#define ACC1(EE, FF)                                                        \
    {                                                                       \
        const float4* wr = (const float4*)&sm.w[wv][(EE) & 63u][0];         \
        const float4 w0 = wr[0], w1 = wr[1], w2 = wr[2], w3 = wr[3];        \
        acc[0]  += (FF) * w0.x;  acc[1]  += (FF) * w0.y;                    \
        acc[2]  += (FF) * w0.z;  acc[3]  += (FF) * w0.w;                    \
        acc[4]  += (FF) * w1.x;  acc[5]  += (FF) * w1.y;                    \
        acc[6]  += (FF) * w1.z;  acc[7]  += (FF) * w1.w;                    \
        acc[8]  += (FF) * w2.x;  acc[9]  += (FF) * w2.y;                    \
        acc[10] += (FF) * w2.z;  acc[11] += (FF) * w2.w;                    \
        acc[12] += (FF) * w3.x;  acc[13] += (FF) * w3.y;  acc[14] += (FF) * w3.z; \
    }

    for (int j0 = 0; j0 < Apad; j0 += 4) {
        const uint4 e = *(const uint4*)&sm.am[wv][j0];    // broadcast b128
        const float f0 = x[(size_t)(e.x >> 6) * DF + d];  // 4 coalesced 256B
        const float f1 = x[(size_t)(e.y >> 6) * DF + d];  //  gathers in flight
        const float f2 = x[(size_t)(e.z >> 6) * DF + d];
        const float f3 = x[(size_t)(e.w >> 6) * DF + d];
        ACC1(e.x, f0) ACC1(e.y, f1) ACC1(e.z, f2) ACC1(e.w, f3)
    }
#undef ACC1

    // bf16 row into wt tile: wt[wv*WTS + k*64 + d] (128B contiguous per wave)
    unsigned short* wrow = sm.wt + wv * WTS + d;
    #pragma unroll
    for (int k = 0; k < KP; ++k)
        wrow[k * DF] = f2bf(acc[k]);

    __syncthreads();                                 // the ONLY block barrier
    if (wv >= 4) return;

    // ---- phase 2: wave wv -> out cols [wv*16, wv*16+16), all 16 rows real
    const int cl = lane & 15, q = lane >> 4;
    f32x4 dacc = (f32x4){0.f, 0.f, 0.f, 0.f};
    #pragma unroll 6
    for (int ks = 0; ks < 30; ++ks) {
        // A: lane holds wt[r=cl][32ks + 8q + j], j=0..7 (16B contiguous)
        const bf16x8 a = *(const bf16x8*)&sm.wt[cl * WTS + ks * 32 + q * 8];
        // B: pre-swizzled chunk (4ks+q)*64 + (wv*16+cl)
        union { uint4 u; bf16x8 v; } bu;
        bu.u = wBf[(4 * ks + q) * 64 + wv * 16 + cl];
        dacc = __builtin_amdgcn_mfma_f32_16x16x32_bf16(a, bu.v, dacc, 0, 0, 0);
    }
    // D: row = q*4+i (query), col = wv*16+cl
    #pragma unroll
    for (int i = 0; i < 4; ++i)
        out[(size_t)(n0 + q * 4 + i) * 64 + wv * 16 + cl] = dacc[i];
}

// ---------------------------------------------------------------------------
extern "C" void kernel_launch(void* const* d_in, const int* in_sizes, int n_in,
                              void* d_out, int out_size, void* d_ws, size_t ws_size,
                              hipStream_t stream) {
    const float* qp   = (const float*)d_in[0];
    const float* sp   = (const float*)d_in[1];
    const int*   nb   = (const int*)d_in[2];
    const float* x    = (const float*)d_in[3];
    const float* kpts = (const float*)d_in[4];
    const float* W    = (const float*)d_in[5];
    float* out = (float*)d_out;

    uint4* wBf = (uint4*)d_ws;   // 122880 B pre-swizzled bf16 weight

    hipLaunchKernelGGL(conv_w, dim3(30), dim3(256), 0, stream, W, wBf);
    hipLaunchKernelGGL(kpconv_fused, dim3(NQ / 16), dim3(1024), 0, stream,
                       qp, sp, nb, x, kpts, wBf, out);
}

// Round 8
// 136.225 us; speedup vs baseline: 1.1828x; 1.0318x over previous
//
#include <hip/hip_runtime.h>

#define NQ 50000
#define NS 50000
#define MNB 32
#define KP 15
#define DF 64
#define WTS 968             // wt LDS row stride in ushorts (960 + 8 pad)
#define WQS 40              // wq k-row stride in ushorts (32 + 8 pad, 80B = 16B-aligned)

typedef __bf16 bf16x8 __attribute__((ext_vector_type(8)));
typedef float  f32x4  __attribute__((ext_vector_type(4)));

__device__ __forceinline__ unsigned short f2bf(float f) {
    union { float f; unsigned int u; } v; v.f = f;
    unsigned int u = v.u;
    return (unsigned short)((u + 0x7FFFu + ((u >> 16) & 1u)) >> 16);  // RNE
}

// ---------------------------------------------------------------------------
// Preconvert x [NS,64] f32 -> bf16 (plain row-major ushort table).
// ---------------------------------------------------------------------------
__global__ __launch_bounds__(256) void conv_x(const float* __restrict__ x,
                                              unsigned int* __restrict__ xb, int n4) {
    const int i = blockIdx.x * 256 + threadIdx.x;
    if (i * 4 + 3 < n4) {
        const float4* s = (const float4*)x + i * 2;
        const float4 a0 = s[0], a1 = s[1];
        uint4 o;
        o.x = (unsigned)f2bf(a0.x) | ((unsigned)f2bf(a0.y) << 16);
        o.y = (unsigned)f2bf(a0.z) | ((unsigned)f2bf(a0.w) << 16);
        o.z = (unsigned)f2bf(a1.x) | ((unsigned)f2bf(a1.y) << 16);
        o.w = (unsigned)f2bf(a1.z) | ((unsigned)f2bf(a1.w) << 16);
        ((uint4*)xb)[i] = o;
    }
}

// ---------------------------------------------------------------------------
// Preconvert weight -> bf16, B-fragment-swizzled in PERMUTED K-order:
//   kappa = (k*16 + t)*4 + cb  maps to original row  k*64 + cb*16 + t
// (k = kernel point, t = channel-within-16, cb = channel block). This makes
// the fused kernel's D->wt scatter a contiguous b64 per lane.
// uint4 chunk tc*64+c holds Wperm[tc*8+j][c], j=0..7; MFMA step ks, quad q:
// B-fragment = chunk (4ks+q)*64 + col.
// ---------------------------------------------------------------------------
__global__ __launch_bounds__(256) void conv_w(const float* __restrict__ W,
                                              uint4* __restrict__ wBf) {
    const int chunk = blockIdx.x * 256 + threadIdx.x;
    if (chunk >= 7680) return;
    const int tc = chunk >> 6, c = chunk & 63;
    union { unsigned short s[8]; uint4 u; } pk;
    #pragma unroll
    for (int j = 0; j < 8; ++j) {
        const int kappa = tc * 8 + j;
        const int k  = kappa >> 6;
        const int cb = kappa & 3;
        const int t  = (kappa >> 2) & 15;
        pk.s[j] = f2bf(W[(size_t)(k * 64 + cb * 16 + t) * 64 + c]);
    }
    wBf[chunk] = pk.u;
}

// ---------------------------------------------------------------------------
// Fused KPConv: 16 queries / 1024-thread block (grid 3125 exact), 1 query/wave.
// Phase A: lane (kh,m) computes 8 influence weights for neighbor m, writes
//   bf16 wq[k][m] tile + clamped ids (own slot only -> no barrier).
// Phase B: per-query aggregation AS MFMA: weighted[16k x 64c] =
//   wq[16k x 32m] (A-frag from LDS) x feats[32m x 64c] (B-frags gathered
//   straight from the bf16 x table). 4 MFMAs/query. D written to wt in
//   permuted-K order, one b64 per (lane, k-row).
// Phase 2: out[16,64] = wt[16,960] @ Wperm, waves 0-3, 30 MFMAs each.
// ---------------------------------------------------------------------------
__global__ __launch_bounds__(1024, 8) void kpconv_fused(
    const float* __restrict__ qp, const float* __restrict__ sp,
    const int* __restrict__ nb, const unsigned short* __restrict__ xbu,
    const float* __restrict__ kpts, const uint4* __restrict__ wBf,
    float* __restrict__ out)
{
    __shared__ struct {
        __align__(16) unsigned short wt[16 * WTS];   // 30976 B: GEMM-2 A tile
        __align__(16) unsigned short wq[16][16 * WQS]; // 20480 B: bf16 w[k][m]
        __align__(16) unsigned int   ids[16][MNB];   //  2048 B: clamped ids
    } sm;                                            // 53504 B -> 2 blocks/CU

    const int tid  = threadIdx.x;
    const int lane = tid & 63, wv = tid >> 6;        // wv = query slot 0..15
    const int kh = lane >> 5, m = lane & 31;
    const int n0 = blockIdx.x * 16;
    const int n  = n0 + wv;                          // exact grid

    // ---- phase A: lane (kh,m) -> kpoints kh*8..kh*8+7 for neighbor m
    const int id = nb[n * MNB + m];
    const float qx = qp[n * 3 + 0], qy = qp[n * 3 + 1], qz = qp[n * 3 + 2];
    float sx = 1e6f, sy = 1e6f, sz = 1e6f;
    if (id < NS) { sx = sp[id * 3 + 0]; sy = sp[id * 3 + 1]; sz = sp[id * 3 + 2]; }
    const float rx = sx - qx, ry = sy - qy, rz = sz - qz;
    float wk[8];
    #pragma unroll
    for (int j = 0; j < 8; ++j) {
        const int k = kh * 8 + j;
        const int kc = (k < KP) ? k : 0;
        const float dx = rx - kpts[kc * 3 + 0];      // kpts uniform -> s_load
        const float dy = ry - kpts[kc * 3 + 1];
        const float dz = rz - kpts[kc * 3 + 2];
        wk[j] = fmaxf(1.0f - sqrtf(dx * dx + dy * dy + dz * dz), 0.0f);
    }
    #pragma unroll
    for (int j = 0; j < 8; ++j) {
        const int k = kh * 8 + j;
        if (k < KP) sm.wq[wv][k * WQS + m] = f2bf(wk[j]);   // row 15 left garbage
    }
    if (kh == 0) sm.ids[wv][m] = (id < NS) ? (unsigned)id : 0u;  // w=0 anyway

    // ---- phase B: aggregation MFMA (same-wave LDS ordering, no barrier)
    const int cl = lane & 15, q = lane >> 4;
    union { uint4 u; bf16x8 v; } af;
    af.u = *(const uint4*)&sm.wq[wv][cl * WQS + q * 8];   // A[r=kpoint cl][m=8q+j]
    const uint4 ia = *(const uint4*)&sm.ids[wv][q * 8];     // broadcast b128
    const uint4 ib = *(const uint4*)&sm.ids[wv][q * 8 + 4];
    const f32x4 zero = (f32x4){0.f, 0.f, 0.f, 0.f};
    f32x4 acc1[4];
    #pragma unroll
    for (int cb = 0; cb < 4; ++cb) {
        // B[m=8q+j][c=cb*16+cl] = xb[id_{8q+j}][cb*16+cl], 8 ushort gathers
        const unsigned v0 = xbu[(size_t)ia.x * DF + cb * 16 + cl];
        const unsigned v1 = xbu[(size_t)ia.y * DF + cb * 16 + cl];
        const unsigned v2 = xbu[(size_t)ia.z * DF + cb * 16 + cl];
        const unsigned v3 = xbu[(size_t)ia.w * DF + cb * 16 + cl];
        const unsigned v4 = xbu[(size_t)ib.x * DF + cb * 16 + cl];
        const unsigned v5 = xbu[(size_t)ib.y * DF + cb * 16 + cl];
        const unsigned v6 = xbu[(size_t)ib.z * DF + cb * 16 + cl];
        const unsigned v7 = xbu[(size_t)ib.w * DF + cb * 16 + cl];
        union { uint4 u; bf16x8 v; } bf;
        bf.u.x = v0 | (v1 << 16);
        bf.u.y = v2 | (v3 << 16);
        bf.u.z = v4 | (v5 << 16);
        bf.u.w = v6 | (v7 << 16);
        acc1[cb] = __builtin_amdgcn_mfma_f32_16x16x32_bf16(af.v, bf.v, zero, 0, 0, 0);
    }

    // D[row=4q+i][col=cb*16+cl] -> wt at kappa=((4q+i)*16+cl)*4+cb: b64/lane
    #pragma unroll
    for (int i = 0; i < 4; ++i) {
        const int k = q * 4 + i;
        if (k < KP) {
            union { unsigned short s[4]; uint2 u; } pk;
            #pragma unroll
            for (int cb = 0; cb < 4; ++cb) pk.s[cb] = f2bf(acc1[cb][i]);
            *(uint2*)&sm.wt[wv * WTS + (k * 16 + cl) * 4] = pk.u;
        }
    }
    __syncthreads();                                 // the ONLY block barrier
    if (wv >= 4) return;

    // ---- phase 2: wave wv -> out cols [wv*16, wv*16+16), 16 query rows
    f32x4 dacc = (f32x4){0.f, 0.f, 0.f, 0.f};
    #pragma unroll 6
    for (int ks = 0; ks < 30; ++ks) {
        const bf16x8 a = *(const bf16x8*)&sm.wt[cl * WTS + ks * 32 + q * 8];
        union { uint4 u; bf16x8 v; } bu;
        bu.u = wBf[(4 * ks + q) * 64 + wv * 16 + cl];
        dacc = __builtin_amdgcn_mfma_f32_16x16x32_bf16(a, bu.v, dacc, 0, 0, 0);
    }
    #pragma unroll
    for (int i = 0; i < 4; ++i)
        out[(size_t)(n0 + q * 4 + i) * 64 + wv * 16 + cl] = dacc[i];
}

// ---------------------------------------------------------------------------
extern "C" void kernel_launch(void* const* d_in, const int* in_sizes, int n_in,
                              void* d_out, int out_size, void* d_ws, size_t ws_size,
                              hipStream_t stream) {
    const float* qp   = (const float*)d_in[0];
    const float* sp   = (const float*)d_in[1];
    const int*   nb   = (const int*)d_in[2];
    const float* x    = (const float*)d_in[3];
    const float* kpts = (const float*)d_in[4];
    const float* W    = (const float*)d_in[5];
    float* out = (float*)d_out;

    // ws: [0, 122880) pre-swizzled bf16 weight; then bf16 x table (6.4 MB)
    uint4*          wBf = (uint4*)d_ws;
    unsigned int*   xb  = (unsigned int*)((char*)d_ws + 122880);
    unsigned short* xbu = (unsigned short*)xb;

    hipLaunchKernelGGL(conv_x, dim3(1563), dim3(256), 0, stream, x, xb, NS * DF / 2);
    hipLaunchKernelGGL(conv_w, dim3(30), dim3(256), 0, stream, W, wBf);
    hipLaunchKernelGGL(kpconv_fused, dim3(NQ / 16), dim3(1024), 0, stream,
                       qp, sp, nb, xbu, kpts, wBf, out);
}

// Round 9
// 129.290 us; speedup vs baseline: 1.2462x; 1.0536x over previous
//
#include <hip/hip_runtime.h>

#define NQ 50000
#define NS 50000
#define MNB 32
#define KP 15
#define DF 64
#define WTS 968             // wt LDS row stride in ushorts (960 + 8 pad)
#define WQS 40              // wq k-row stride in ushorts (32 + 8 pad)

typedef __bf16 bf16x8 __attribute__((ext_vector_type(8)));
typedef float  f32x4  __attribute__((ext_vector_type(4)));

__device__ __forceinline__ unsigned short bf1(float f) {
    union { __bf16 h; unsigned short s; } r; r.h = (__bf16)f; return r.s;
}
__device__ __forceinline__ unsigned pk2(float a, float b) {   // v_cvt_pk_bf16_f32
    union { __bf16 h[2]; unsigned u; } r;
    r.h[0] = (__bf16)a; r.h[1] = (__bf16)b; return r.u;
}

// ---------------------------------------------------------------------------
// One preconvert kernel, block-split:
//  blocks [0,3125): x [NS,64] f32 -> bf16 channel-interleaved: row id,
//    channel c=cb*16+cl stored at ushort index cl*4+cb  (so the 4 cb-values
//    of one (id,cl) are a single uint2).
//  blocks [3125,3155): weight -> bf16 B-fragment-swizzled in permuted K-order
//    kappa=(k*16+t)*4+cb <- original row k*64+cb*16+t; uint4 chunk tc*64+c
//    holds Wperm[tc*8+j][c]; MFMA step ks, quad q: chunk (4ks+q)*64+col.
// ---------------------------------------------------------------------------
__global__ __launch_bounds__(256) void preconv(
    const float* __restrict__ x, const float* __restrict__ W,
    unsigned short* __restrict__ xbp, uint4* __restrict__ wBf)
{
    const int b = blockIdx.x;
    if (b < NS / 16) {
        const int row = b * 16 + (threadIdx.x >> 4);
        const int cl  = threadIdx.x & 15;
        const float f0 = x[row * DF + 0 * 16 + cl];   // 64B-coalesced per cb
        const float f1 = x[row * DF + 1 * 16 + cl];
        const float f2 = x[row * DF + 2 * 16 + cl];
        const float f3 = x[row * DF + 3 * 16 + cl];
        uint2 o; o.x = pk2(f0, f1); o.y = pk2(f2, f3);
        *(uint2*)&xbp[row * DF + cl * 4] = o;
    } else {
        const int chunk = (b - NS / 16) * 256 + threadIdx.x;
        if (chunk >= 7680) return;
        const int tc = chunk >> 6, c = chunk & 63;
        union { unsigned short s[8]; uint4 u; } pk;
        #pragma unroll
        for (int j = 0; j < 8; ++j) {
            const int kappa = tc * 8 + j;
            const int k  = kappa >> 6;
            const int cb = kappa & 3;
            const int t  = (kappa >> 2) & 15;
            pk.s[j] = bf1(W[(size_t)(k * 64 + cb * 16 + t) * 64 + c]);
        }
        wBf[chunk] = pk.u;
    }
}

// ---------------------------------------------------------------------------
// Fused KPConv: 16 queries / 1024-thread block (grid 3125 exact), 1 query/wave.
// Phase A: lane (kh,m) computes 8 influence weights for neighbor m -> bf16
//   wq[k][m] tile + clamped ids (own slot only -> no barrier).
// Phase B: aggregation as MFMA: weighted[16k x 64c] = wq[16k x 32m] x
//   feats[32m x 64c]. Feats: 8 uint2 gathers/lane from the interleaved bf16
//   x table, transposed into 4 B-fragments with 16 v_perm_b32. 4 MFMAs/query.
//   D -> wt in permuted-K order, one b64 per (lane, k-row).
// Phase 2: out[16,64] = wt[16,960] @ Wperm, waves 0-3, 30 MFMAs each.
// ---------------------------------------------------------------------------
__global__ __launch_bounds__(1024, 8) void kpconv_fused(
    const float* __restrict__ qp, const float* __restrict__ sp,
    const int* __restrict__ nb, const uint2* __restrict__ xb2,
    const float* __restrict__ kpts, const uint4* __restrict__ wBf,
    float* __restrict__ out)
{
    __shared__ struct {
        __align__(16) unsigned short wt[16 * WTS];     // 30976 B: GEMM-2 A tile
        __align__(16) unsigned short wq[16][16 * WQS]; // 20480 B: bf16 w[k][m]
        __align__(16) unsigned int   ids[16][MNB];     //  2048 B: clamped ids
    } sm;                                              // 53504 B

    const int tid  = threadIdx.x;
    const int lane = tid & 63, wv = tid >> 6;          // wv = query slot 0..15
    const int kh = lane >> 5, m = lane & 31;
    const int n0 = blockIdx.x * 16;
    const int n  = n0 + wv;                            // exact grid

    // ---- phase A: lane (kh,m) -> kpoints kh*8..kh*8+7 for neighbor m
    const int id = nb[n * MNB + m];
    const float qx = qp[n * 3 + 0], qy = qp[n * 3 + 1], qz = qp[n * 3 + 2];
    float sx = 1e6f, sy = 1e6f, sz = 1e6f;
    if (id < NS) { sx = sp[id * 3 + 0]; sy = sp[id * 3 + 1]; sz = sp[id * 3 + 2]; }
    const float rx = sx - qx, ry = sy - qy, rz = sz - qz;
    #pragma unroll
    for (int j = 0; j < 8; ++j) {
        const int k = kh * 8 + j;
        const int kc = (k < KP) ? k : 0;
        const float dx = rx - kpts[kc * 3 + 0];        // kpts uniform -> s_load
        const float dy = ry - kpts[kc * 3 + 1];
        const float dz = rz - kpts[kc * 3 + 2];
        const float wkj = fmaxf(1.0f - sqrtf(dx * dx + dy * dy + dz * dz), 0.0f);
        if (k < KP) sm.wq[wv][k * WQS + m] = bf1(wkj); // row 15 left garbage
    }
    if (kh == 0) sm.ids[wv][m] = (id < NS) ? (unsigned)id : 0u;  // w=0 anyway

    // ---- phase B: aggregation MFMA (same-wave LDS ordering, no barrier)
    const int cl = lane & 15, q = lane >> 4;
    union { uint4 u; bf16x8 v; } af;
    af.u = *(const uint4*)&sm.wq[wv][cl * WQS + q * 8];  // A[r=cl][m=8q+j]
    const uint4 ia = *(const uint4*)&sm.ids[wv][q * 8];  // broadcast b128
    const uint4 ib = *(const uint4*)&sm.ids[wv][q * 8 + 4];
    // 8 neighbor gathers: uint2 = channels (cb=0..3)*16+cl of row id
    const uint2 r0 = xb2[(size_t)ia.x * 16 + cl];
    const uint2 r1 = xb2[(size_t)ia.y * 16 + cl];
    const uint2 r2 = xb2[(size_t)ia.z * 16 + cl];
    const uint2 r3 = xb2[(size_t)ia.w * 16 + cl];
    const uint2 r4 = xb2[(size_t)ib.x * 16 + cl];
    const uint2 r5 = xb2[(size_t)ib.y * 16 + cl];
    const uint2 r6 = xb2[(size_t)ib.z * 16 + cl];
    const uint2 r7 = xb2[(size_t)ib.w * 16 + cl];
    // transpose to B-fragments: dword t of frag(cb) = val[2t].cb | val[2t+1].cb<<16
    #define PRM(hi, lo, sel) __builtin_amdgcn_perm((hi), (lo), (sel))
    const unsigned S0 = 0x05040100u, S1 = 0x07060302u;
    union { uint4 u; bf16x8 v; } bf[4];
    bf[0].u = (uint4){PRM(r1.x, r0.x, S0), PRM(r3.x, r2.x, S0), PRM(r5.x, r4.x, S0), PRM(r7.x, r6.x, S0)};
    bf[1].u = (uint4){PRM(r1.x, r0.x, S1), PRM(r3.x, r2.x, S1), PRM(r5.x, r4.x, S1), PRM(r7.x, r6.x, S1)};
    bf[2].u = (uint4){PRM(r1.y, r0.y, S0), PRM(r3.y, r2.y, S0), PRM(r5.y, r4.y, S0), PRM(r7.y, r6.y, S0)};
    bf[3].u = (uint4){PRM(r1.y, r0.y, S1), PRM(r3.y, r2.y, S1), PRM(r5.y, r4.y, S1), PRM(r7.y, r6.y, S1)};
    #undef PRM
    const f32x4 zero = (f32x4){0.f, 0.f, 0.f, 0.f};
    f32x4 acc1[4];
    #pragma unroll
    for (int cb = 0; cb < 4; ++cb)
        acc1[cb] = __builtin_amdgcn_mfma_f32_16x16x32_bf16(af.v, bf[cb].v, zero, 0, 0, 0);

    // D[row=4q+i][col=cb*16+cl] -> wt at kappa=((4q+i)*16+cl)*4+cb: b64/lane
    #pragma unroll
    for (int i = 0; i < 4; ++i) {
        const int k = q * 4 + i;
        if (k < KP) {
            uint2 pkd;
            pkd.x = pk2(acc1[0][i], acc1[1][i]);
            pkd.y = pk2(acc1[2][i], acc1[3][i]);
            *(uint2*)&sm.wt[wv * WTS + (k * 16 + cl) * 4] = pkd;
        }
    }
    __syncthreads();                                   // the ONLY block barrier
    if (wv >= 4) return;

    // ---- phase 2: wave wv -> out cols [wv*16, wv*16+16), 16 query rows
    f32x4 dacc = (f32x4){0.f, 0.f, 0.f, 0.f};
    #pragma unroll 6
    for (int ks = 0; ks < 30; ++ks) {
        const bf16x8 a = *(const bf16x8*)&sm.wt[cl * WTS + ks * 32 + q * 8];
        union { uint4 u; bf16x8 v; } bu;
        bu.u = wBf[(4 * ks + q) * 64 + wv * 16 + cl];
        dacc = __builtin_amdgcn_mfma_f32_16x16x32_bf16(a, bu.v, dacc, 0, 0, 0);
    }
    #pragma unroll
    for (int i = 0; i < 4; ++i)
        out[(size_t)(n0 + q * 4 + i) * 64 + wv * 16 + cl] = dacc[i];
}

// ---------------------------------------------------------------------------
extern "C" void kernel_launch(void* const* d_in, const int* in_sizes, int n_in,
                              void* d_out, int out_size, void* d_ws, size_t ws_size,
                              hipStream_t stream) {
    const float* qp   = (const float*)d_in[0];
    const float* sp   = (const float*)d_in[1];
    const int*   nb   = (const int*)d_in[2];
    const float* x    = (const float*)d_in[3];
    const float* kpts = (const float*)d_in[4];
    const float* W    = (const float*)d_in[5];
    float* out = (float*)d_out;

    // ws: [0, 122880) pre-swizzled bf16 weight; then interleaved bf16 x (6.4 MB)
    uint4*          wBf = (uint4*)d_ws;
    unsigned short* xbp = (unsigned short*)((char*)d_ws + 122880);

    hipLaunchKernelGGL(preconv, dim3(NS / 16 + 30), dim3(256), 0, stream,
                       x, W, xbp, wBf);
    hipLaunchKernelGGL(kpconv_fused, dim3(NQ / 16), dim3(1024), 0, stream,
                       qp, sp, nb, (const uint2*)xbp, kpts, wBf, out);
}

// Round 10
// 126.503 us; speedup vs baseline: 1.2737x; 1.0220x over previous
//
#include <hip/hip_runtime.h>

#define NQ 50000
#define NS 50000
#define MNB 32
#define KP 15
#define DF 64
#define WTS 968             // wt LDS row stride in ushorts (960 + 8 pad)
#define WQS 40              // wq k-row stride in ushorts (32 + 8 pad)

typedef __bf16 bf16x8 __attribute__((ext_vector_type(8)));
typedef float  f32x4  __attribute__((ext_vector_type(4)));

__device__ __forceinline__ unsigned short bf1(float f) {
    union { __bf16 h; unsigned short s; } r; r.h = (__bf16)f; return r.s;
}
__device__ __forceinline__ unsigned pk2(float a, float b) {   // v_cvt_pk_bf16_f32
    union { __bf16 h[2]; unsigned u; } r;
    r.h[0] = (__bf16)a; r.h[1] = (__bf16)b; return r.u;
}

// ---------------------------------------------------------------------------
// One preconvert kernel, block-split:
//  blocks [0,3125): x [NS,64] f32 -> bf16 channel-interleaved (row id, channel
//    c=cb*16+cl at ushort index cl*4+cb -> uint2 per (id,cl)).
//  blocks [3125,3155): weight -> bf16 B-fragment-swizzled, permuted K-order
//    kappa=(k*16+t)*4+cb <- original row k*64+cb*16+t.
//  block 3155: zero sentinel feature row NS.
// ---------------------------------------------------------------------------
__global__ __launch_bounds__(256) void preconv(
    const float* __restrict__ x, const float* __restrict__ W,
    unsigned short* __restrict__ xbp, uint4* __restrict__ wBf)
{
    const int b = blockIdx.x;
    if (b < NS / 16) {
        const int row = b * 16 + (threadIdx.x >> 4);
        const int cl  = threadIdx.x & 15;
        const float f0 = x[row * DF + 0 * 16 + cl];
        const float f1 = x[row * DF + 1 * 16 + cl];
        const float f2 = x[row * DF + 2 * 16 + cl];
        const float f3 = x[row * DF + 3 * 16 + cl];
        uint2 o; o.x = pk2(f0, f1); o.y = pk2(f2, f3);
        *(uint2*)&xbp[row * DF + cl * 4] = o;
    } else if (b < NS / 16 + 30) {
        const int chunk = (b - NS / 16) * 256 + threadIdx.x;   // < 7680 exact
        const int tc = chunk >> 6, c = chunk & 63;
        union { unsigned short s[8]; uint4 u; } pk;
        #pragma unroll
        for (int j = 0; j < 8; ++j) {
            const int kappa = tc * 8 + j;
            const int k  = kappa >> 6;
            const int cb = kappa & 3;
            const int t  = (kappa >> 2) & 15;
            pk.s[j] = bf1(W[(size_t)(k * 64 + cb * 16 + t) * 64 + c]);
        }
        wBf[chunk] = pk.u;
    } else {
        if (threadIdx.x < 8)
            ((uint4*)(xbp + (size_t)NS * DF))[threadIdx.x] = (uint4){0, 0, 0, 0};
    }
}

// ---------------------------------------------------------------------------
// Fused KPConv: 16 queries / 1024-thread block (grid 3125 exact), 1 query/wave.
// Phase A: lane (kh,m) computes 8 influence weights for neighbor m; the
//   active-neighbor list is compacted via ballot. Compacted position p maps
//   to MFMA K-slot sigma(p) = (p%4)*8 + p/4, so gather-instruction j covers
//   logical positions 4j..4j+3 -> wave-uniform skip when 4j >= A.
//   Inactive neighbors park their all-zero weight columns in tail slots
//   (finite -> no NaN), tail ids point at zeroed sentinel row NS.
// Phase B: aggregation MFMA: weighted[16k x 64c] = wq[16k x 32s] x
//   feats[32s x 64c]; ceil(A/4) of 8 gather groups issued. 4 MFMAs/query.
//   D -> wt in permuted-K order, one b64 per (lane, k-row).
// Phase 2: out[16,64] = wt[16,960] @ Wperm, waves 0-3, 30 MFMAs each.
// ---------------------------------------------------------------------------
__global__ __launch_bounds__(1024, 8) void kpconv_fused(
    const float* __restrict__ qp, const float* __restrict__ sp,
    const int* __restrict__ nb, const uint2* __restrict__ xb2,
    const float* __restrict__ kpts, const uint4* __restrict__ wBf,
    float* __restrict__ out)
{
    __shared__ struct {
        __align__(16) unsigned short wt[16 * WTS];     // 30976 B: GEMM-2 A tile
        __align__(16) unsigned short wq[16][16 * WQS]; // 20480 B: bf16 w[k][slot]
        __align__(16) unsigned int   ids[16][MNB];     //  2048 B: compacted ids
    } sm;                                              // 53504 B

    const int tid  = threadIdx.x;
    const int lane = tid & 63, wv = tid >> 6;          // wv = query slot 0..15
    const int kh = lane >> 5, m = lane & 31;
    const int n0 = blockIdx.x * 16;
    const int n  = n0 + wv;                            // exact grid

    // ---- phase A: lane (kh,m) -> kpoints kh*8..kh*8+7 for neighbor m
    const int id = nb[n * MNB + m];
    const float qx = qp[n * 3 + 0], qy = qp[n * 3 + 1], qz = qp[n * 3 + 2];
    float sx = 1e6f, sy = 1e6f, sz = 1e6f;
    if (id < NS) { sx = sp[id * 3 + 0]; sy = sp[id * 3 + 1]; sz = sp[id * 3 + 2]; }
    const float rx = sx - qx, ry = sy - qy, rz = sz - qz;
    float wk[8], wmax = 0.0f;
    #pragma unroll
    for (int j = 0; j < 8; ++j) {
        const int k = kh * 8 + j;
        const int kc = (k < KP) ? k : 0;
        const float dx = rx - kpts[kc * 3 + 0];        // kpts uniform -> s_load
        const float dy = ry - kpts[kc * 3 + 1];
        const float dz = rz - kpts[kc * 3 + 2];
        wk[j] = fmaxf(1.0f - sqrtf(dx * dx + dy * dy + dz * dz), 0.0f);
        wmax = fmaxf(wmax, wk[j]);
    }
    // compaction: combined 32-bit activity mask (active = either half nonzero)
    const unsigned long long bal = __ballot(wmax > 0.0f);
    const unsigned comb = (unsigned)(bal & 0xFFFFFFFFull) | (unsigned)(bal >> 32);
    const int A = __popc(comb);                        // wave-uniform (SGPR)
    const bool act = (comb >> m) & 1u;
    const unsigned mlow = (1u << m) - 1u;
    const int p = act ? __popc(comb & mlow) : (A + __popc(~comb & mlow));
    const int s = (p & 3) * 8 + (p >> 2);              // K-slot sigma(p)
    // write weight column s (inactive columns are all-zero -> finite)
    #pragma unroll
    for (int j = 0; j < 8; ++j) {
        const int k = kh * 8 + j;
        if (k < KP) sm.wq[wv][k * WQS + s] = bf1(wk[j]);   // k=15 row: garbage OK
    }
    if (kh == 0) sm.ids[wv][p] = act ? (unsigned)id : (unsigned)NS;  // NS = zero row

    // ---- phase B: aggregation MFMA (same-wave LDS ordering, no barrier)
    const int cl = lane & 15, q = lane >> 4;
    union { uint4 u; bf16x8 v; } af;
    af.u = *(const uint4*)&sm.wq[wv][cl * WQS + q * 8];  // A[r=cl][slot=8q+j]
    uint2 r[8];
    #pragma unroll
    for (int j = 0; j < 8; ++j) r[j] = (uint2){0u, 0u};  // bf16 zeros
    #pragma unroll
    for (int j = 0; j < 8; ++j) {
        if (4 * j < A) {                                  // wave-uniform skip
            const unsigned sid = sm.ids[wv][4 * j + q];   // logical pos 4j+q
            r[j] = xb2[(size_t)sid * 16 + cl];            // 4 cb-vals, one b64
        }
    }
    // transpose to B-fragments: frag(cb) dword t = [r2t.cb | r2t+1.cb<<16]
    #define PRM(hi, lo, sel) __builtin_amdgcn_perm((hi), (lo), (sel))
    const unsigned S0 = 0x05040100u, S1 = 0x07060302u;
    union { uint4 u; bf16x8 v; } bf[4];
    bf[0].u = (uint4){PRM(r[1].x, r[0].x, S0), PRM(r[3].x, r[2].x, S0), PRM(r[5].x, r[4].x, S0), PRM(r[7].x, r[6].x, S0)};
    bf[1].u = (uint4){PRM(r[1].x, r[0].x, S1), PRM(r[3].x, r[2].x, S1), PRM(r[5].x, r[4].x, S1), PRM(r[7].x, r[6].x, S1)};
    bf[2].u = (uint4){PRM(r[1].y, r[0].y, S0), PRM(r[3].y, r[2].y, S0), PRM(r[5].y, r[4].y, S0), PRM(r[7].y, r[6].y, S0)};
    bf[3].u = (uint4){PRM(r[1].y, r[0].y, S1), PRM(r[3].y, r[2].y, S1), PRM(r[5].y, r[4].y, S1), PRM(r[7].y, r[6].y, S1)};
    #undef PRM
    const f32x4 zero = (f32x4){0.f, 0.f, 0.f, 0.f};
    f32x4 acc1[4];
    #pragma unroll
    for (int cb = 0; cb < 4; ++cb)
        acc1[cb] = __builtin_amdgcn_mfma_f32_16x16x32_bf16(af.v, bf[cb].v, zero, 0, 0, 0);

    // D[row=4q+i][col=cb*16+cl] -> wt at kappa=((4q+i)*16+cl)*4+cb: b64/lane
    #pragma unroll
    for (int i = 0; i < 4; ++i) {
        const int k = q * 4 + i;
        if (k < KP) {
            uint2 pkd;
            pkd.x = pk2(acc1[0][i], acc1[1][i]);
            pkd.y = pk2(acc1[2][i], acc1[3][i]);
            *(uint2*)&sm.wt[wv * WTS + (k * 16 + cl) * 4] = pkd;
        }
    }
    __syncthreads();                                   // the ONLY block barrier
    if (wv >= 4) return;

    // ---- phase 2: wave wv -> out cols [wv*16, wv*16+16), 16 query rows
    f32x4 dacc = (f32x4){0.f, 0.f, 0.f, 0.f};
    #pragma unroll 6
    for (int ks = 0; ks < 30; ++ks) {
        const bf16x8 a = *(const bf16x8*)&sm.wt[cl * WTS + ks * 32 + q * 8];
        union { uint4 u; bf16x8 v; } bu;
        bu.u = wBf[(4 * ks + q) * 64 + wv * 16 + cl];
        dacc = __builtin_amdgcn_mfma_f32_16x16x32_bf16(a, bu.v, dacc, 0, 0, 0);
    }
    #pragma unroll
    for (int i = 0; i < 4; ++i)
        out[(size_t)(n0 + q * 4 + i) * 64 + wv * 16 + cl] = dacc[i];
}

// ---------------------------------------------------------------------------
extern "C" void kernel_launch(void* const* d_in, const int* in_sizes, int n_in,
                              void* d_out, int out_size, void* d_ws, size_t ws_size,
                              hipStream_t stream) {
    const float* qp   = (const float*)d_in[0];
    const float* sp   = (const float*)d_in[1];
    const int*   nb   = (const int*)d_in[2];
    const float* x    = (const float*)d_in[3];
    const float* kpts = (const float*)d_in[4];
    const float* W    = (const float*)d_in[5];
    float* out = (float*)d_out;

    // ws: [0, 122880) pre-swizzled bf16 weight; then interleaved bf16 x with
    // one extra zeroed sentinel row (NS+1 rows).
    uint4*          wBf = (uint4*)d_ws;
    unsigned short* xbp = (unsigned short*)((char*)d_ws + 122880);

    hipLaunchKernelGGL(preconv, dim3(NS / 16 + 31), dim3(256), 0, stream,
                       x, W, xbp, wBf);
    hipLaunchKernelGGL(kpconv_fused, dim3(NQ / 16), dim3(1024), 0, stream,
                       qp, sp, nb, (const uint2*)xbp, kpts, wBf, out);
}

// Round 11
// 124.543 us; speedup vs baseline: 1.2937x; 1.0157x over previous
//
#include <hip/hip_runtime.h>

#define NQ 50000
#define NS 50000
#define MNB 32
#define KP 15
#define DF 64
#define WTS 968             // wt LDS row stride in ushorts (960 + 8 pad)
#define WQS 40              // wq k-row stride in ushorts (32 + 8 pad)

typedef __bf16 bf16x8 __attribute__((ext_vector_type(8)));
typedef float  f32x4  __attribute__((ext_vector_type(4)));
typedef float  f32x2  __attribute__((ext_vector_type(2)));

__device__ __forceinline__ unsigned short bf1(float f) {
    union { __bf16 h; unsigned short s; } r; r.h = (__bf16)f; return r.s;
}
__device__ __forceinline__ unsigned pk2(float a, float b) {   // v_cvt_pk_bf16_f32
    union { __bf16 h[2]; unsigned u; } r;
    r.h[0] = (__bf16)a; r.h[1] = (__bf16)b; return r.u;
}

// ---------------------------------------------------------------------------
// Weight preconvert only (x is gathered raw now): W [960][64] f32 -> bf16,
// B-fragment-swizzled, K-order = plain flat index kappa = k*64 + cl*4 + cb
// (identity, because fused maps MFMA column (cb,cl) <-> channel cl*4+cb).
// uint4 chunk tc*64+c holds W[tc*8+j][c]; MFMA step ks, quad q uses chunk
// (4ks+q)*64 + col.  Grid = 30 x 256 exact.
// ---------------------------------------------------------------------------
__global__ __launch_bounds__(256) void conv_w(const float* __restrict__ W,
                                              uint4* __restrict__ wBf) {
    const int chunk = blockIdx.x * 256 + threadIdx.x;   // < 7680
    const int tc = chunk >> 6, c = chunk & 63;
    union { unsigned short s[8]; uint4 u; } pk;
    #pragma unroll
    for (int j = 0; j < 8; ++j)
        pk.s[j] = bf1(W[(size_t)(tc * 8 + j) * 64 + c]);
    wBf[chunk] = pk.u;
}

// ---------------------------------------------------------------------------
// Fused KPConv: 16 queries / 1024-thread block (grid 3125 exact), 1 query/wave.
// Phase A: lane (kh,m) computes influence weights for neighbor m in packed
//   f32x2 pairs (kpoints k, k+4), raw v_sqrt; active neighbors compacted via
//   ballot, compacted pos p -> K-slot sigma(p)=(p%4)*8+p/4 so gather group j
//   covers logical 4j..4j+3 (wave-uniform skip when 4j >= A). Inactive slots:
//   zero weight columns, ids clamped to 0 (w==0 nullifies junk features).
// Phase B: aggregation MFMA: weighted[16k x 64c] = wq[16k x 32s] x feats.
//   Feats: float4 gathers straight from x (channels cl*4+{0..3}), converted
//   with v_cvt_pk_bf16_f32, two groups of 4 to cap VGPRs. 4 MFMAs/query.
//   D -> wt at kappa = k*64 + cl*4 + cb, one b64 per (lane, k-row).
// Phase 2: out[16,64] = wt[16,960] @ Wswz, waves 0-3, 30 MFMAs each.
// ---------------------------------------------------------------------------
__global__ __launch_bounds__(1024, 8) void kpconv_fused(
    const float* __restrict__ qp, const float* __restrict__ sp,
    const int* __restrict__ nb, const float* __restrict__ x,
    const float* __restrict__ kpts, const uint4* __restrict__ wBf,
    float* __restrict__ out)
{
    __shared__ struct {
        __align__(16) unsigned short wt[16 * WTS];     // 30976 B: GEMM-2 A tile
        __align__(16) unsigned short wq[16][16 * WQS]; // 20480 B: bf16 w[k][slot]
        __align__(16) unsigned int   ids[16][MNB];     //  2048 B: compacted ids
    } sm;                                              // 53504 B

    const int tid  = threadIdx.x;
    const int lane = tid & 63;
    const int wv   = __builtin_amdgcn_readfirstlane(tid >> 6);  // scalar slot
    const int kh = lane >> 5, m = lane & 31;
    const int n0 = blockIdx.x * 16;
    const int n  = n0 + wv;                            // scalar -> s_load addrs

    // ---- phase A: lane (kh,m) -> kpoints kh*8..kh*8+7 for neighbor m
    const int id = nb[n * MNB + m];
    const float qx = qp[n * 3 + 0], qy = qp[n * 3 + 1], qz = qp[n * 3 + 2];
    float sx = 1e6f, sy = 1e6f, sz = 1e6f;
    if (id < NS) { sx = sp[id * 3 + 0]; sy = sp[id * 3 + 1]; sz = sp[id * 3 + 2]; }
    const float rx = sx - qx, ry = sy - qy, rz = sz - qz;
    float wk[8], wmax = 0.0f;
    #pragma unroll
    for (int jj = 0; jj < 4; ++jj) {                   // pairs (k, k+4)
        const int ka = kh * 8 + jj;
        const int kb0 = ka + 4;
        const int kb = (kb0 < KP) ? kb0 : 0;           // k=15 -> phantom of k=0
        const f32x2 dx = (f32x2){rx, rx} - (f32x2){kpts[ka*3+0], kpts[kb*3+0]};
        const f32x2 dy = (f32x2){ry, ry} - (f32x2){kpts[ka*3+1], kpts[kb*3+1]};
        const f32x2 dz = (f32x2){rz, rz} - (f32x2){kpts[ka*3+2], kpts[kb*3+2]};
        const f32x2 d2 = dx * dx + dy * dy + dz * dz;  // v_pk_mul/fma
        const float wa = fmaxf(1.0f - __builtin_amdgcn_sqrtf(d2.x), 0.0f);
        const float wb = fmaxf(1.0f - __builtin_amdgcn_sqrtf(d2.y), 0.0f);
        wk[jj] = wa; wk[jj + 4] = wb;
        wmax = fmaxf(wmax, fmaxf(wa, wb));
    }
    // compaction (phantom k=15 activity == k=0's -> no false positives)
    const unsigned long long bal = __ballot(wmax > 0.0f);
    const unsigned comb = (unsigned)(bal & 0xFFFFFFFFull) | (unsigned)(bal >> 32);
    const int A = __popc(comb);                        // wave-uniform (SGPR)
    const bool act = (comb >> m) & 1u;
    const unsigned mlow = (1u << m) - 1u;
    const int p = act ? __popc(comb & mlow) : (A + __popc(~comb & mlow));
    const int s = (p & 3) * 8 + (p >> 2);              // K-slot sigma(p)
    const float gate = act ? 1.0f : 0.0f;              // zero inactive columns
    #pragma unroll
    for (int jj = 0; jj < 8; ++jj)                     // unconditional: row 15
        sm.wq[wv][(kh * 8 + jj) * WQS + s] = bf1(wk[jj] * gate);  // finite junk
    if (kh == 0) sm.ids[wv][p] = act ? (unsigned)id : 0u;

    // ---- phase B: aggregation MFMA (same-wave LDS ordering, no barrier)
    const int cl = lane & 15, q = lane >> 4;
    union { uint4 u; bf16x8 v; } af;
    af.u = *(const uint4*)&sm.wq[wv][cl * WQS + q * 8];  // A[r=cl][slot=8q+j]
    const float4* __restrict__ x4 = (const float4*)x;    // row = 16 float4
    union { uint4 u; bf16x8 v; } bfr[4];
    {   // group 0: logical neighbors 0..15 (gather groups j=0..3)
        float4 r[4];
        #pragma unroll
        for (int j = 0; j < 4; ++j) {
            r[j] = (float4){0.f, 0.f, 0.f, 0.f};
            if (4 * j < A)                               // wave-uniform skip
                r[j] = x4[(size_t)sm.ids[wv][4 * j + q] * 16 + cl];
        }
        #pragma unroll
        for (int cb = 0; cb < 4; ++cb) {
            bfr[cb].u.x = pk2(((const float*)&r[0])[cb], ((const float*)&r[1])[cb]);
            bfr[cb].u.y = pk2(((const float*)&r[2])[cb], ((const float*)&r[3])[cb]);
        }
    }
    {   // group 1: logical neighbors 16..31 (gather groups j=4..7)
        float4 r[4];
        #pragma unroll
        for (int j = 0; j < 4; ++j) {
            r[j] = (float4){0.f, 0.f, 0.f, 0.f};
            if (4 * (j + 4) < A)
                r[j] = x4[(size_t)sm.ids[wv][4 * (j + 4) + q] * 16 + cl];
        }
        #pragma unroll
        for (int cb = 0; cb < 4; ++cb) {
            bfr[cb].u.z = pk2(((const float*)&r[0])[cb], ((const float*)&r[1])[cb]);
            bfr[cb].u.w = pk2(((const float*)&r[2])[cb], ((const float*)&r[3])[cb]);
        }
    }
    const f32x4 zero = (f32x4){0.f, 0.f, 0.f, 0.f};
    f32x4 acc1[4];
    #pragma unroll
    for (int cb = 0; cb < 4; ++cb)
        acc1[cb] = __builtin_amdgcn_mfma_f32_16x16x32_bf16(af.v, bfr[cb].v, zero, 0, 0, 0);

    // D[row=4q+i][col=(cb,cl)] -> wt at kappa = k*64 + cl*4 + cb: b64/lane
    #pragma unroll
    for (int i = 0; i < 4; ++i) {
        const int k = q * 4 + i;
        if (k < KP) {
            uint2 pkd;
            pkd.x = pk2(acc1[0][i], acc1[1][i]);
            pkd.y = pk2(acc1[2][i], acc1[3][i]);
            *(uint2*)&sm.wt[wv * WTS + k * 64 + cl * 4] = pkd;
        }
    }
    __syncthreads();                                   // the ONLY block barrier
    if (wv >= 4) return;

    // ---- phase 2: wave wv -> out cols [wv*16, wv*16+16), 16 query rows
    f32x4 dacc = (f32x4){0.f, 0.f, 0.f, 0.f};
    #pragma unroll 6
    for (int ks = 0; ks < 30; ++ks) {
        const bf16x8 a = *(const bf16x8*)&sm.wt[cl * WTS + ks * 32 + q * 8];
        union { uint4 u; bf16x8 v; } bu;
        bu.u = wBf[(4 * ks + q) * 64 + wv * 16 + cl];
        dacc = __builtin_amdgcn_mfma_f32_16x16x32_bf16(a, bu.v, dacc, 0, 0, 0);
    }
    #pragma unroll
    for (int i = 0; i < 4; ++i)
        out[(size_t)(n0 + q * 4 + i) * 64 + wv * 16 + cl] = dacc[i];
}

// ---------------------------------------------------------------------------
extern "C" void kernel_launch(void* const* d_in, const int* in_sizes, int n_in,
                              void* d_out, int out_size, void* d_ws, size_t ws_size,
                              hipStream_t stream) {
    const float* qp   = (const float*)d_in[0];
    const float* sp   = (const float*)d_in[1];
    const int*   nb   = (const int*)d_in[2];
    const float* x    = (const float*)d_in[3];
    const float* kpts = (const float*)d_in[4];
    const float* W    = (const float*)d_in[5];
    float* out = (float*)d_out;

    uint4* wBf = (uint4*)d_ws;   // 122880 B pre-swizzled bf16 weight

    hipLaunchKernelGGL(conv_w, dim3(30), dim3(256), 0, stream, W, wBf);
    hipLaunchKernelGGL(kpconv_fused, dim3(NQ / 16), dim3(1024), 0, stream,
                       qp, sp, nb, x, kpts, wBf, out);
}